// Round 3
// baseline (379.542 us; speedup 1.0000x reference)
//
#include <hip/hip_runtime.h>
#include <math.h>

#define HIDDEN 1024
#define INTER  1408
#define NEXP   8
#define NTOK   2048

typedef short s16x8 __attribute__((ext_vector_type(8)));   // 8 bf16 MFMA operand
typedef float f32x4 __attribute__((ext_vector_type(4)));   // MFMA accumulator

static __device__ __forceinline__ short f2b(float f) {
  union { float f; unsigned u; } v; v.f = f;
  unsigned u = v.u;
  unsigned r = (u + 0x7FFFu + ((u >> 16) & 1u)) >> 16;   // RNE
  return (short)r;
}

// Async global->LDS, 16B per lane. LDS dest must be wave-uniform; lane i lands
// at lds + 16*i.
static __device__ __forceinline__ void gll16(void* lds, const void* g) {
  __builtin_amdgcn_global_load_lds(
      (const __attribute__((address_space(1))) void*)g,
      (__attribute__((address_space(3))) void*)lds, 16, 0, 0);
}

// ---------------------------------------------------------------------------
// Router: one wave per token, fp32 exact. Packs slot (0 = top-1, 1 = top-2)
// into bit 16 of the token entry so down can store without atomics.
// ---------------------------------------------------------------------------
__global__ __launch_bounds__(256) void router_kernel(
    const float* __restrict__ x, const float* __restrict__ rw,
    int* __restrict__ counts, int* __restrict__ tok_list,
    float* __restrict__ w_list)
{
  int wave = threadIdx.x >> 6;
  int lane = threadIdx.x & 63;
  int t = blockIdx.x * 4 + wave;
  if (t >= NTOK) return;
  const float* xt = x + (size_t)t * HIDDEN;
  float xr[16];
#pragma unroll
  for (int i = 0; i < 16; ++i) xr[i] = xt[lane + 64 * i];
  float logits[NEXP];
#pragma unroll
  for (int e = 0; e < NEXP; ++e) {
    const float* w = rw + e * HIDDEN;
    float acc = 0.f;
#pragma unroll
    for (int i = 0; i < 16; ++i) acc = fmaf(xr[i], w[lane + 64 * i], acc);
#pragma unroll
    for (int off = 32; off > 0; off >>= 1) acc += __shfl_xor(acc, off);
    logits[e] = acc;
  }
  if (lane == 0) {
    float mx = logits[0];
#pragma unroll
    for (int e = 1; e < NEXP; ++e) mx = fmaxf(mx, logits[e]);
    float p[NEXP];
#pragma unroll
    for (int e = 0; e < NEXP; ++e) p[e] = expf(logits[e] - mx);
    int i0 = 0;
#pragma unroll
    for (int e = 1; e < NEXP; ++e) if (p[e] > p[i0]) i0 = e;
    int i1 = (i0 == 0) ? 1 : 0;
#pragma unroll
    for (int e = 0; e < NEXP; ++e) { if (e != i0 && p[e] > p[i1]) i1 = e; }
    float denom = p[i0] + p[i1];
    int pos0 = atomicAdd(&counts[i0], 1);
    tok_list[i0 * NTOK + pos0] = t;                 // slot 0
    w_list[i0 * NTOK + pos0] = p[i0] / denom;
    int pos1 = atomicAdd(&counts[i1], 1);
    tok_list[i1 * NTOK + pos1] = t | (1 << 16);     // slot 1
    w_list[i1 * NTOK + pos1] = p[i1] / denom;
  }
}

__global__ void prefix_kernel(const int* __restrict__ counts, int* __restrict__ base)
{
  if (threadIdx.x == 0 && blockIdx.x == 0) {
    int s = 0;
    for (int e = 0; e < NEXP; ++e) { base[e] = s; s += counts[e]; }
  }
}

// ---------------------------------------------------------------------------
// x fp32 -> bf16 (same layout).
// ---------------------------------------------------------------------------
__global__ __launch_bounds__(256) void convx_kernel(
    const float* __restrict__ x, short* __restrict__ xb)
{
  int i = blockIdx.x * 256 + threadIdx.x;
  const float4* p = (const float4*)x;
  float4 a = p[2 * i], b = p[2 * i + 1];
  s16x8 o;
  o[0] = f2b(a.x); o[1] = f2b(a.y); o[2] = f2b(a.z); o[3] = f2b(a.w);
  o[4] = f2b(b.x); o[5] = f2b(b.y); o[6] = f2b(b.z); o[7] = f2b(b.w);
  *(s16x8*)(xb + 8 * (size_t)i) = o;
}

// ---------------------------------------------------------------------------
// Transpose-convert: fp32 [e][K][N] -> bf16 [e][N][K].
// ---------------------------------------------------------------------------
__global__ __launch_bounds__(256) void tconv_kernel(
    const float* __restrict__ in, short* __restrict__ out, int K, int N)
{
  int e = blockIdx.z;
  const float* ie = in + (size_t)e * K * N;
  short* oe = out + (size_t)e * K * N;
  int k0 = blockIdx.y * 64, n0 = blockIdx.x * 64;
  __shared__ float t[64][65];
  int tid = threadIdx.x;
  int c4 = (tid & 15) * 4, r = tid >> 4;
#pragma unroll
  for (int p = 0; p < 4; ++p) {
    float4 v = *(const float4*)(ie + (size_t)(k0 + r + p * 16) * N + n0 + c4);
    t[r + p * 16][c4 + 0] = v.x;
    t[r + p * 16][c4 + 1] = v.y;
    t[r + p * 16][c4 + 2] = v.z;
    t[r + p * 16][c4 + 3] = v.w;
  }
  __syncthreads();
  int rn = tid >> 2, ck = (tid & 3) * 16;
  s16x8 o0, o1;
#pragma unroll
  for (int j = 0; j < 8; ++j) o0[j] = f2b(t[ck + j][rn]);
#pragma unroll
  for (int j = 0; j < 8; ++j) o1[j] = f2b(t[ck + 8 + j][rn]);
  short* op = oe + (size_t)(n0 + rn) * K + k0 + ck;
  *(s16x8*)(op) = o0;
  *(s16x8*)(op + 8) = o1;
}

// ---------------------------------------------------------------------------
// Phase A: H = silu(X@Wg)*(X@Wu). Tile M=64 N=128 BK=32, 4 waves (2x2), each
// wave 2x4 grid of 16x16x32 bf16 MFMAs for gate AND up. All staging via
// global_load_lds (16B/lane) with XOR-swizzled chunks (2-way banks = free).
// ---------------------------------------------------------------------------
__global__ __launch_bounds__(256, 3) void gateup_mfma(
    const short* __restrict__ xb, const short* __restrict__ wgT,
    const short* __restrict__ wuT,
    const int* __restrict__ counts, const int* __restrict__ base,
    const int* __restrict__ tok_list, short* __restrict__ hbuf)
{
  int e = blockIdx.z;
  int cnt = counts[e];
  int m0 = blockIdx.y * 64;
  if (m0 >= cnt) return;
  int n0 = blockIdx.x * 128;

  __shared__ short As[64 * 32];
  __shared__ short Bg[128 * 32];
  __shared__ short Bu[128 * 32];
  __shared__ int toks[64];

  int tid = threadIdx.x;
  if (tid < 64) {
    int r = m0 + tid;
    toks[tid] = tok_list[e * NTOK + (r < cnt ? r : cnt - 1)] & 0xFFFF;
  }
  __syncthreads();

  int wv = tid >> 6, lane = tid & 63;
  // --- staging: lane i of wave covers row rbase + i/4, physical chunk i%4;
  //     global side loads logical chunk (i&3)^((i>>3)&3)  (XOR swizzle)
  int lr = lane >> 2;
  int glog = (lane & 3) ^ ((lane >> 3) & 3);
  const short* gA = xb + (size_t)toks[wv * 16 + lr] * HIDDEN + glog * 8;
  int rb0 = wv * 32 + lr, rb1 = rb0 + 16;
  const short* gG0 = wgT + ((size_t)e * INTER + n0 + rb0) * HIDDEN + glog * 8;
  const short* gG1 = wgT + ((size_t)e * INTER + n0 + rb1) * HIDDEN + glog * 8;
  const short* gU0 = wuT + ((size_t)e * INTER + n0 + rb0) * HIDDEN + glog * 8;
  const short* gU1 = wuT + ((size_t)e * INTER + n0 + rb1) * HIDDEN + glog * 8;
  short* lA  = &As[wv * 512];
  short* lG0 = &Bg[wv * 1024];
  short* lG1 = &Bg[wv * 1024 + 512];
  short* lU0 = &Bu[wv * 1024];
  short* lU1 = &Bu[wv * 1024 + 512];

  // --- fragment reads: row r, logical chunk q -> physical q ^ ((ml>>1)&3)
  int q = lane >> 4, ml = lane & 15;
  int chk = q ^ ((ml >> 1) & 3);
  int wm = wv & 1, wn = wv >> 1;
  const short* ard = &As[(wm * 32 + ml) * 32 + chk * 8];
  const short* grd = &Bg[(wn * 64 + ml) * 32 + chk * 8];
  const short* urd = &Bu[(wn * 64 + ml) * 32 + chk * 8];

  f32x4 accg[2][4], accu[2][4];
#pragma unroll
  for (int i = 0; i < 2; ++i)
#pragma unroll
    for (int j = 0; j < 4; ++j) { accg[i][j] = (f32x4)0.f; accu[i][j] = (f32x4)0.f; }

  for (int k0 = 0; k0 < HIDDEN; k0 += 32) {
    __syncthreads();                 // prev iter's fragment reads done
    gll16(lA,  gA  + k0);
    gll16(lG0, gG0 + k0);
    gll16(lG1, gG1 + k0);
    gll16(lU0, gU0 + k0);
    gll16(lU1, gU1 + k0);
    __syncthreads();                 // drains vmcnt(0): LDS tiles ready

    s16x8 af[2], gf[4], uf[4];
#pragma unroll
    for (int i = 0; i < 2; ++i) af[i] = *(const s16x8*)(ard + i * 512);
#pragma unroll
    for (int j = 0; j < 4; ++j) {
      gf[j] = *(const s16x8*)(grd + j * 512);
      uf[j] = *(const s16x8*)(urd + j * 512);
    }
#pragma unroll
    for (int i = 0; i < 2; ++i)
#pragma unroll
      for (int j = 0; j < 4; ++j) {
        accg[i][j] = __builtin_amdgcn_mfma_f32_16x16x32_bf16(af[i], gf[j], accg[i][j], 0, 0, 0);
        accu[i][j] = __builtin_amdgcn_mfma_f32_16x16x32_bf16(af[i], uf[j], accu[i][j], 0, 0, 0);
      }
  }

  int hb = base[e];
#pragma unroll
  for (int i = 0; i < 2; ++i)
#pragma unroll
    for (int ii = 0; ii < 4; ++ii) {
      int r = m0 + wm * 32 + i * 16 + q * 4 + ii;
      if (r < cnt) {
        short* hp = hbuf + (size_t)(hb + r) * INTER + n0 + wn * 64 + ml;
#pragma unroll
        for (int j = 0; j < 4; ++j) {
          float g = accg[i][j][ii], u = accu[i][j][ii];
          float h = (g / (1.f + __expf(-g))) * u;
          hp[j * 16] = f2b(h);
        }
      }
    }
}

// ---------------------------------------------------------------------------
// Phase B: Y = H @ Wd, scale by router weight, plain stores into per-slot
// buffer ybuf[2][NTOK][HIDDEN] (no atomics; every (slot,token) written once).
// ---------------------------------------------------------------------------
__global__ __launch_bounds__(256, 4) void down_mfma(
    const short* __restrict__ hbuf, const short* __restrict__ wdT,
    const int* __restrict__ counts, const int* __restrict__ base,
    const int* __restrict__ tok_list, const float* __restrict__ w_list,
    float* __restrict__ ybuf)
{
  int e = blockIdx.z;
  int cnt = counts[e];
  int m0 = blockIdx.y * 64;
  if (m0 >= cnt) return;
  int n0 = blockIdx.x * 128;

  __shared__ short As[64 * 32];
  __shared__ short Bs[128 * 32];

  int tid = threadIdx.x;
  int hb = base[e];
  int wv = tid >> 6, lane = tid & 63;
  int lr = lane >> 2;
  int glog = (lane & 3) ^ ((lane >> 3) & 3);
  int ra = m0 + wv * 16 + lr; if (ra >= cnt) ra = cnt - 1;
  const short* gA = hbuf + (size_t)(hb + ra) * INTER + glog * 8;
  int rb0 = wv * 32 + lr, rb1 = rb0 + 16;
  const short* gB0 = wdT + ((size_t)e * HIDDEN + n0 + rb0) * INTER + glog * 8;
  const short* gB1 = wdT + ((size_t)e * HIDDEN + n0 + rb1) * INTER + glog * 8;
  short* lA  = &As[wv * 512];
  short* lB0 = &Bs[wv * 1024];
  short* lB1 = &Bs[wv * 1024 + 512];

  int q = lane >> 4, ml = lane & 15;
  int chk = q ^ ((ml >> 1) & 3);
  int wm = wv & 1, wn = wv >> 1;
  const short* ard = &As[(wm * 32 + ml) * 32 + chk * 8];
  const short* brd = &Bs[(wn * 64 + ml) * 32 + chk * 8];

  f32x4 acc[2][4];
#pragma unroll
  for (int i = 0; i < 2; ++i)
#pragma unroll
    for (int j = 0; j < 4; ++j) acc[i][j] = (f32x4)0.f;

  for (int k0 = 0; k0 < INTER; k0 += 32) {
    __syncthreads();
    gll16(lA,  gA  + k0);
    gll16(lB0, gB0 + k0);
    gll16(lB1, gB1 + k0);
    __syncthreads();

    s16x8 af[2], bf[4];
#pragma unroll
    for (int i = 0; i < 2; ++i) af[i] = *(const s16x8*)(ard + i * 512);
#pragma unroll
    for (int j = 0; j < 4; ++j) bf[j] = *(const s16x8*)(brd + j * 512);
#pragma unroll
    for (int i = 0; i < 2; ++i)
#pragma unroll
      for (int j = 0; j < 4; ++j)
        acc[i][j] = __builtin_amdgcn_mfma_f32_16x16x32_bf16(af[i], bf[j], acc[i][j], 0, 0, 0);
  }

#pragma unroll
  for (int i = 0; i < 2; ++i)
#pragma unroll
    for (int ii = 0; ii < 4; ++ii) {
      int r = m0 + wm * 32 + i * 16 + q * 4 + ii;
      if (r < cnt) {
        int ent = tok_list[e * NTOK + r];
        int tok = ent & 0xFFFF, slot = ent >> 16;
        float wgt = w_list[e * NTOK + r];
        float* yp = ybuf + ((size_t)slot * NTOK + tok) * HIDDEN + n0 + wn * 64 + ml;
#pragma unroll
        for (int j = 0; j < 4; ++j)
          yp[j * 16] = acc[i][j][ii] * wgt;
      }
    }
}

// ---------------------------------------------------------------------------
// out = ybuf[0] + ybuf[1]   (writes every element -> no out memset needed)
// ---------------------------------------------------------------------------
__global__ __launch_bounds__(256) void combine_kernel(
    const float* __restrict__ ybuf, float* __restrict__ out)
{
  size_t i = (size_t)blockIdx.x * 256 + threadIdx.x;
  float4 a = ((const float4*)ybuf)[i];
  float4 b = ((const float4*)(ybuf + (size_t)NTOK * HIDDEN))[i];
  float4 o;
  o.x = a.x + b.x; o.y = a.y + b.y; o.z = a.z + b.z; o.w = a.w + b.w;
  ((float4*)out)[i] = o;
}

// ---------------------------------------------------------------------------
// ws layout (bytes):
//   0..32           counts[8]
//   32..64          base[8]
//   64..65600       tok_list[8][2048]  (token | slot<<16)
//   65600..131136   w_list[8][2048]
//   131136          xb   bf16 [2048][1024]      (4 MB)
//   +4 MB           wgT  bf16 [8][1408][1024]   (23.07 MB)  } ybuf (16 MB fp32)
//                                                           } aliases wgT after
//                                                           } gateup completes
//   +23.07 MB       wuT  bf16 [8][1408][1024]
//   +23.07 MB       wdT  bf16 [8][1024][1408]
//   +23.07 MB       hbuf bf16 [4096][1408]      (11.5 MB)
//   total ~85.1 MB (same as round 2)
// ---------------------------------------------------------------------------
extern "C" void kernel_launch(void* const* d_in, const int* in_sizes, int n_in,
                              void* d_out, int out_size, void* d_ws, size_t ws_size,
                              hipStream_t stream)
{
  const float* x  = (const float*)d_in[0];
  const float* rw = (const float*)d_in[1];
  const float* wg = (const float*)d_in[2];
  const float* wu = (const float*)d_in[3];
  const float* wd = (const float*)d_in[4];
  float* out = (float*)d_out;

  char* ws = (char*)d_ws;
  int*   counts   = (int*)(ws);
  int*   base     = (int*)(ws + 32);
  int*   tok_list = (int*)(ws + 64);
  float* w_list   = (float*)(ws + 64 + NEXP * NTOK * 4);
  size_t off = 64 + 2 * (size_t)NEXP * NTOK * 4;
  short* xb  = (short*)(ws + off);  off += (size_t)NTOK * HIDDEN * 2;
  short* wgT = (short*)(ws + off);  off += (size_t)NEXP * HIDDEN * INTER * 2;
  short* wuT = (short*)(ws + off);  off += (size_t)NEXP * HIDDEN * INTER * 2;
  short* wdT = (short*)(ws + off);  off += (size_t)NEXP * HIDDEN * INTER * 2;
  short* hbuf = (short*)(ws + off);
  float* ybuf = (float*)wgT;   // wgT dead after gateup; 16 MB fits in its 23 MB

  hipMemsetAsync(ws, 0, 64, stream);   // counts + base

  convx_kernel<<<(NTOK * HIDDEN / 8) / 256, 256, 0, stream>>>(x, xb);
  {
    dim3 g(INTER / 64, HIDDEN / 64, NEXP);   // wg/wu: K=HIDDEN, N=INTER
    tconv_kernel<<<g, 256, 0, stream>>>(wg, wgT, HIDDEN, INTER);
    tconv_kernel<<<g, 256, 0, stream>>>(wu, wuT, HIDDEN, INTER);
  }
  {
    dim3 g(HIDDEN / 64, INTER / 64, NEXP);   // wd: K=INTER, N=HIDDEN
    tconv_kernel<<<g, 256, 0, stream>>>(wd, wdT, INTER, HIDDEN);
  }

  router_kernel<<<NTOK / 4, 256, 0, stream>>>(x, rw, counts, tok_list, w_list);
  prefix_kernel<<<1, 64, 0, stream>>>(counts, base);

  dim3 gA(INTER / 128, NTOK / 64, NEXP);
  gateup_mfma<<<gA, 256, 0, stream>>>(xb, wgT, wuT, counts, base, tok_list, hbuf);

  dim3 gB(HIDDEN / 128, NTOK / 64, NEXP);
  down_mfma<<<gB, 256, 0, stream>>>(hbuf, wdT, counts, base, tok_list, w_list, ybuf);

  combine_kernel<<<(NTOK * HIDDEN / 4) / 256, 256, 0, stream>>>(ybuf, out);
}

// Round 4
// 326.547 us; speedup vs baseline: 1.1623x; 1.1623x over previous
//
#include <hip/hip_runtime.h>
#include <math.h>

#define HIDDEN 1024
#define INTER  1408
#define NEXP   8
#define NTOK   2048
#define KSPLIT_LEN 704   // INTER/2

typedef short s16x8 __attribute__((ext_vector_type(8)));   // 8 bf16 MFMA operand
typedef float f32x4 __attribute__((ext_vector_type(4)));   // MFMA accumulator

static __device__ __forceinline__ short f2b(float f) {
  union { float f; unsigned u; } v; v.f = f;
  unsigned u = v.u;
  unsigned r = (u + 0x7FFFu + ((u >> 16) & 1u)) >> 16;   // RNE
  return (short)r;
}

// ---------------------------------------------------------------------------
// Router: one wave per token, fp32 exact. Packs slot (0 = top-1, 1 = top-2)
// into bit 16 of the token entry so down can store without atomics.
// ---------------------------------------------------------------------------
__global__ __launch_bounds__(256) void router_kernel(
    const float* __restrict__ x, const float* __restrict__ rw,
    int* __restrict__ counts, int* __restrict__ tok_list,
    float* __restrict__ w_list)
{
  int wave = threadIdx.x >> 6;
  int lane = threadIdx.x & 63;
  int t = blockIdx.x * 4 + wave;
  if (t >= NTOK) return;
  const float* xt = x + (size_t)t * HIDDEN;
  float xr[16];
#pragma unroll
  for (int i = 0; i < 16; ++i) xr[i] = xt[lane + 64 * i];
  float logits[NEXP];
#pragma unroll
  for (int e = 0; e < NEXP; ++e) {
    const float* w = rw + e * HIDDEN;
    float acc = 0.f;
#pragma unroll
    for (int i = 0; i < 16; ++i) acc = fmaf(xr[i], w[lane + 64 * i], acc);
#pragma unroll
    for (int off = 32; off > 0; off >>= 1) acc += __shfl_xor(acc, off);
    logits[e] = acc;
  }
  if (lane == 0) {
    float mx = logits[0];
#pragma unroll
    for (int e = 1; e < NEXP; ++e) mx = fmaxf(mx, logits[e]);
    float p[NEXP];
#pragma unroll
    for (int e = 0; e < NEXP; ++e) p[e] = expf(logits[e] - mx);
    int i0 = 0;
#pragma unroll
    for (int e = 1; e < NEXP; ++e) if (p[e] > p[i0]) i0 = e;
    int i1 = (i0 == 0) ? 1 : 0;
#pragma unroll
    for (int e = 0; e < NEXP; ++e) { if (e != i0 && p[e] > p[i1]) i1 = e; }
    float denom = p[i0] + p[i1];
    int pos0 = atomicAdd(&counts[i0], 1);
    tok_list[i0 * NTOK + pos0] = t;                 // slot 0
    w_list[i0 * NTOK + pos0] = p[i0] / denom;
    int pos1 = atomicAdd(&counts[i1], 1);
    tok_list[i1 * NTOK + pos1] = t | (1 << 16);     // slot 1
    w_list[i1 * NTOK + pos1] = p[i1] / denom;
  }
}

__global__ void prefix_kernel(const int* __restrict__ counts, int* __restrict__ base)
{
  if (threadIdx.x == 0 && blockIdx.x == 0) {
    int s = 0;
    for (int e = 0; e < NEXP; ++e) { base[e] = s; s += counts[e]; }
  }
}

// ---------------------------------------------------------------------------
// x fp32 -> bf16 (same layout).
// ---------------------------------------------------------------------------
__global__ __launch_bounds__(256) void convx_kernel(
    const float* __restrict__ x, short* __restrict__ xb)
{
  int i = blockIdx.x * 256 + threadIdx.x;
  const float4* p = (const float4*)x;
  float4 a = p[2 * i], b = p[2 * i + 1];
  s16x8 o;
  o[0] = f2b(a.x); o[1] = f2b(a.y); o[2] = f2b(a.z); o[3] = f2b(a.w);
  o[4] = f2b(b.x); o[5] = f2b(b.y); o[6] = f2b(b.z); o[7] = f2b(b.w);
  *(s16x8*)(xb + 8 * (size_t)i) = o;
}

// ---------------------------------------------------------------------------
// Transpose-convert: fp32 [e][K][N] -> bf16 [e][N][K].
// ---------------------------------------------------------------------------
__global__ __launch_bounds__(256) void tconv_kernel(
    const float* __restrict__ in, short* __restrict__ out, int K, int N)
{
  int e = blockIdx.z;
  const float* ie = in + (size_t)e * K * N;
  short* oe = out + (size_t)e * K * N;
  int k0 = blockIdx.y * 64, n0 = blockIdx.x * 64;
  __shared__ float t[64][65];
  int tid = threadIdx.x;
  int c4 = (tid & 15) * 4, r = tid >> 4;
#pragma unroll
  for (int p = 0; p < 4; ++p) {
    float4 v = *(const float4*)(ie + (size_t)(k0 + r + p * 16) * N + n0 + c4);
    t[r + p * 16][c4 + 0] = v.x;
    t[r + p * 16][c4 + 1] = v.y;
    t[r + p * 16][c4 + 2] = v.z;
    t[r + p * 16][c4 + 3] = v.w;
  }
  __syncthreads();
  int rn = tid >> 2, ck = (tid & 3) * 16;
  s16x8 o0, o1;
#pragma unroll
  for (int j = 0; j < 8; ++j) o0[j] = f2b(t[ck + j][rn]);
#pragma unroll
  for (int j = 0; j < 8; ++j) o1[j] = f2b(t[ck + 8 + j][rn]);
  short* op = oe + (size_t)(n0 + rn) * K + k0 + ck;
  *(s16x8*)(op) = o0;
  *(s16x8*)(op + 8) = o1;
}

// ---------------------------------------------------------------------------
// Staging geometry (shared by both GEMMs), XOR-swizzled LDS [row][4 chunks]:
//   phys chunk p of row r holds logical chunk p ^ ((r>>1)&3).
//   Thread t stages row r = t>>1, phys chunks {2h, 2h+1}, h = t&1: the two
//   logical chunks form one contiguous 32B global block (two 16B loads).
//   Fragment read (lane ml, k-quad q): phys chunk q ^ ((ml>>1)&3) -> 2-way
//   bank aliasing only (free, m136); measured 0 conflicts in r3.
// ---------------------------------------------------------------------------

// ---------------------------------------------------------------------------
// Phase A: H = silu(X@Wg)*(X@Wu). Tile M=128 N=128 BK=32, 4 waves (2x2),
// each wave 4x4 MFMAs (16x16x32) for gate AND up. Register-staged prefetch:
// globals for k+1 issued after the LDS-ready barrier, in flight across the
// whole compute phase. Flat grid, XCD-swizzled so the m-blocks sharing one
// (e,n) weight strip land on the same XCD's L2.
// ---------------------------------------------------------------------------
__global__ __launch_bounds__(256, 2) void gateup_mfma(
    const short* __restrict__ xb, const short* __restrict__ wgT,
    const short* __restrict__ wuT,
    const int* __restrict__ counts, const int* __restrict__ base,
    const int* __restrict__ tok_list, short* __restrict__ hbuf)
{
  // grid = 8 xcd * 16 m * 11 g-hi = 1408; g = (e,n) in 0..87
  int id = blockIdx.x;
  int xcd = id & 7;
  int rest = id >> 3;
  int mslot = rest & 15;
  int g = (rest >> 4) * 8 + xcd;
  int e = g / 11;
  int n0 = (g - e * 11) * 128;
  int cnt = counts[e];
  int m0 = mslot * 128;
  if (m0 >= cnt) return;

  __shared__ short As[128 * 32];
  __shared__ short Bg[128 * 32];
  __shared__ short Bu[128 * 32];
  __shared__ int toks[128];

  int tid = threadIdx.x;
  if (tid < 128) {
    int r = m0 + tid;
    toks[tid] = tok_list[e * NTOK + (r < cnt ? r : cnt - 1)] & 0xFFFF;
  }
  __syncthreads();

  // staging addresses
  int sr = tid >> 1;             // 0..127
  int h = tid & 1;
  int key = (sr >> 1) & 3;
  int pair = ((2 * h) ^ key) >> 1;           // which 32B global block
  int sw = (key & 1) * 8;                    // swap c0/c1 on write
  const short* gA = xb + (size_t)toks[sr] * HIDDEN + pair * 16;
  const short* gG = wgT + ((size_t)e * INTER + n0 + sr) * HIDDEN + pair * 16;
  const short* gU = wuT + ((size_t)e * INTER + n0 + sr) * HIDDEN + pair * 16;
  short* wA0 = &As[sr * 32 + h * 16 + sw];
  short* wA1 = &As[sr * 32 + h * 16 + (8 - sw)];
  short* wG0 = &Bg[sr * 32 + h * 16 + sw];
  short* wG1 = &Bg[sr * 32 + h * 16 + (8 - sw)];
  short* wU0 = &Bu[sr * 32 + h * 16 + sw];
  short* wU1 = &Bu[sr * 32 + h * 16 + (8 - sw)];

  // fragment read addresses
  int wv = tid >> 6, lane = tid & 63;
  int wm = wv & 1, wn = wv >> 1;
  int q = lane >> 4, ml = lane & 15;
  int chk = q ^ ((ml >> 1) & 3);
  const short* ard = &As[(wm * 64 + ml) * 32 + chk * 8];
  const short* grd = &Bg[(wn * 64 + ml) * 32 + chk * 8];
  const short* urd = &Bu[(wn * 64 + ml) * 32 + chk * 8];

  f32x4 accg[4][4], accu[4][4];
#pragma unroll
  for (int i = 0; i < 4; ++i)
#pragma unroll
    for (int j = 0; j < 4; ++j) { accg[i][j] = (f32x4)0.f; accu[i][j] = (f32x4)0.f; }

  // preload k=0
  s16x8 a0 = *(const s16x8*)(gA);     s16x8 a1 = *(const s16x8*)(gA + 8);
  s16x8 g0 = *(const s16x8*)(gG);     s16x8 g1 = *(const s16x8*)(gG + 8);
  s16x8 u0 = *(const s16x8*)(gU);     s16x8 u1 = *(const s16x8*)(gU + 8);

  for (int k0 = 0; k0 < HIDDEN; k0 += 32) {
    __syncthreads();                 // prev iter's fragment reads done
    *(s16x8*)wA0 = a0; *(s16x8*)wA1 = a1;
    *(s16x8*)wG0 = g0; *(s16x8*)wG1 = g1;
    *(s16x8*)wU0 = u0; *(s16x8*)wU1 = u1;
    __syncthreads();                 // LDS ready; no globals in flight here

    int kn = (k0 + 32) & (HIDDEN - 1);     // wraps to 0 on last iter (harmless)
    a0 = *(const s16x8*)(gA + kn);     a1 = *(const s16x8*)(gA + kn + 8);
    g0 = *(const s16x8*)(gG + kn);     g1 = *(const s16x8*)(gG + kn + 8);
    u0 = *(const s16x8*)(gU + kn);     u1 = *(const s16x8*)(gU + kn + 8);

    s16x8 af[4], gf[4], uf[4];
#pragma unroll
    for (int i = 0; i < 4; ++i) af[i] = *(const s16x8*)(ard + i * 16 * 32);
#pragma unroll
    for (int j = 0; j < 4; ++j) {
      gf[j] = *(const s16x8*)(grd + j * 16 * 32);
      uf[j] = *(const s16x8*)(urd + j * 16 * 32);
    }
#pragma unroll
    for (int i = 0; i < 4; ++i)
#pragma unroll
      for (int j = 0; j < 4; ++j) {
        accg[i][j] = __builtin_amdgcn_mfma_f32_16x16x32_bf16(af[i], gf[j], accg[i][j], 0, 0, 0);
        accu[i][j] = __builtin_amdgcn_mfma_f32_16x16x32_bf16(af[i], uf[j], accu[i][j], 0, 0, 0);
      }
  }

  int hb = base[e];
#pragma unroll
  for (int i = 0; i < 4; ++i)
#pragma unroll
    for (int ii = 0; ii < 4; ++ii) {
      int r = m0 + wm * 64 + i * 16 + q * 4 + ii;
      if (r < cnt) {
        short* hp = hbuf + (size_t)(hb + r) * INTER + n0 + wn * 64 + ml;
#pragma unroll
        for (int j = 0; j < 4; ++j) {
          float gg = accg[i][j][ii], uu = accu[i][j][ii];
          float hh = (gg / (1.f + __expf(-gg))) * uu;
          hp[j * 16] = f2b(hh);
        }
      }
    }
}

// ---------------------------------------------------------------------------
// Phase B: Y = H @ Wd, K-split x2 for parallelism; scaled partials stored to
// ybuf[slot*2+ks][token] with plain dwords (no atomics). Same staging/swizzle
// /prefetch structure as gateup.
// ---------------------------------------------------------------------------
__global__ __launch_bounds__(256, 3) void down_mfma(
    const short* __restrict__ hbuf, const short* __restrict__ wdT,
    const int* __restrict__ counts, const int* __restrict__ base,
    const int* __restrict__ tok_list, const float* __restrict__ w_list,
    float* __restrict__ ybuf)
{
  // grid = 8 xcd * 16 m * 16 g-hi = 2048; g = (e,ks,n) in 0..127
  int id = blockIdx.x;
  int xcd = id & 7;
  int rest = id >> 3;
  int mslot = rest & 15;
  int g = (rest >> 4) * 8 + xcd;
  int e = g >> 4;
  int ks = (g >> 3) & 1;
  int n0 = (g & 7) * 128;
  int cnt = counts[e];
  int m0 = mslot * 128;
  if (m0 >= cnt) return;

  __shared__ short As[128 * 32];
  __shared__ short Bs[128 * 32];

  int tid = threadIdx.x;
  int hb = base[e];
  int kbeg = ks * KSPLIT_LEN, kend = kbeg + KSPLIT_LEN;

  int sr = tid >> 1;
  int h = tid & 1;
  int key = (sr >> 1) & 3;
  int pair = ((2 * h) ^ key) >> 1;
  int sw = (key & 1) * 8;
  int ra = m0 + sr; if (ra >= cnt) ra = cnt - 1;
  const short* gA = hbuf + (size_t)(hb + ra) * INTER + pair * 16;
  const short* gB = wdT + ((size_t)e * HIDDEN + n0 + sr) * INTER + pair * 16;
  short* wA0 = &As[sr * 32 + h * 16 + sw];
  short* wA1 = &As[sr * 32 + h * 16 + (8 - sw)];
  short* wB0 = &Bs[sr * 32 + h * 16 + sw];
  short* wB1 = &Bs[sr * 32 + h * 16 + (8 - sw)];

  int wv = tid >> 6, lane = tid & 63;
  int wm = wv & 1, wn = wv >> 1;
  int q = lane >> 4, ml = lane & 15;
  int chk = q ^ ((ml >> 1) & 3);
  const short* ard = &As[(wm * 64 + ml) * 32 + chk * 8];
  const short* brd = &Bs[(wn * 64 + ml) * 32 + chk * 8];

  f32x4 acc[4][4];
#pragma unroll
  for (int i = 0; i < 4; ++i)
#pragma unroll
    for (int j = 0; j < 4; ++j) acc[i][j] = (f32x4)0.f;

  s16x8 a0 = *(const s16x8*)(gA + kbeg);  s16x8 a1 = *(const s16x8*)(gA + kbeg + 8);
  s16x8 b0 = *(const s16x8*)(gB + kbeg);  s16x8 b1 = *(const s16x8*)(gB + kbeg + 8);

  for (int k0 = kbeg; k0 < kend; k0 += 32) {
    __syncthreads();
    *(s16x8*)wA0 = a0; *(s16x8*)wA1 = a1;
    *(s16x8*)wB0 = b0; *(s16x8*)wB1 = b1;
    __syncthreads();

    int kn = k0 + 32; if (kn >= kend) kn = kbeg;
    a0 = *(const s16x8*)(gA + kn);  a1 = *(const s16x8*)(gA + kn + 8);
    b0 = *(const s16x8*)(gB + kn);  b1 = *(const s16x8*)(gB + kn + 8);

    s16x8 af[4], bf[4];
#pragma unroll
    for (int i = 0; i < 4; ++i) af[i] = *(const s16x8*)(ard + i * 16 * 32);
#pragma unroll
    for (int j = 0; j < 4; ++j) bf[j] = *(const s16x8*)(brd + j * 16 * 32);
#pragma unroll
    for (int i = 0; i < 4; ++i)
#pragma unroll
      for (int j = 0; j < 4; ++j)
        acc[i][j] = __builtin_amdgcn_mfma_f32_16x16x32_bf16(af[i], bf[j], acc[i][j], 0, 0, 0);
  }

#pragma unroll
  for (int i = 0; i < 4; ++i)
#pragma unroll
    for (int ii = 0; ii < 4; ++ii) {
      int r = m0 + wm * 64 + i * 16 + q * 4 + ii;
      if (r < cnt) {
        int ent = tok_list[e * NTOK + r];
        int tok = ent & 0xFFFF, slot = ent >> 16;
        float wgt = w_list[e * NTOK + r];
        float* yp = ybuf + ((size_t)(slot * 2 + ks) * NTOK + tok) * HIDDEN
                    + n0 + wn * 64 + ml;
#pragma unroll
        for (int j = 0; j < 4; ++j)
          yp[j * 16] = acc[i][j][ii] * wgt;
      }
    }
}

// ---------------------------------------------------------------------------
// out = sum of 4 ybuf slabs (every element written -> no out memset needed)
// ---------------------------------------------------------------------------
__global__ __launch_bounds__(256) void combine_kernel(
    const float* __restrict__ ybuf, float* __restrict__ out)
{
  size_t i = (size_t)blockIdx.x * 256 + threadIdx.x;
  const size_t S = (size_t)NTOK * HIDDEN / 4;
  float4 a = ((const float4*)ybuf)[i];
  float4 b = ((const float4*)ybuf)[i + S];
  float4 c = ((const float4*)ybuf)[i + 2 * S];
  float4 d = ((const float4*)ybuf)[i + 3 * S];
  float4 o;
  o.x = (a.x + b.x) + (c.x + d.x);
  o.y = (a.y + b.y) + (c.y + d.y);
  o.z = (a.z + b.z) + (c.z + d.z);
  o.w = (a.w + b.w) + (c.w + d.w);
  ((float4*)out)[i] = o;
}

// ---------------------------------------------------------------------------
// ws layout (bytes):
//   0..32           counts[8]
//   32..64          base[8]
//   64..65600       tok_list[8][2048]  (token | slot<<16)
//   65600..131136   w_list[8][2048]
//   131136          xb   bf16 [2048][1024]      (4 MB)
//   +4 MB           wgT  bf16 [8][1408][1024]   (23.07 MB) } ybuf[4] (32 MB
//   +23.07 MB       wuT  bf16 [8][1408][1024]   (23.07 MB) } fp32) aliases
//                                                          } wgT+wuT after
//                                                          } gateup completes
//   +23.07 MB       wdT  bf16 [8][1024][1408]
//   +23.07 MB       hbuf bf16 [4096][1408]      (11.5 MB)
//   total ~85.1 MB
// ---------------------------------------------------------------------------
extern "C" void kernel_launch(void* const* d_in, const int* in_sizes, int n_in,
                              void* d_out, int out_size, void* d_ws, size_t ws_size,
                              hipStream_t stream)
{
  const float* x  = (const float*)d_in[0];
  const float* rw = (const float*)d_in[1];
  const float* wg = (const float*)d_in[2];
  const float* wu = (const float*)d_in[3];
  const float* wd = (const float*)d_in[4];
  float* out = (float*)d_out;

  char* ws = (char*)d_ws;
  int*   counts   = (int*)(ws);
  int*   base     = (int*)(ws + 32);
  int*   tok_list = (int*)(ws + 64);
  float* w_list   = (float*)(ws + 64 + NEXP * NTOK * 4);
  size_t off = 64 + 2 * (size_t)NEXP * NTOK * 4;
  short* xb  = (short*)(ws + off);  off += (size_t)NTOK * HIDDEN * 2;
  short* wgT = (short*)(ws + off);  off += (size_t)NEXP * HIDDEN * INTER * 2;
  short* wuT = (short*)(ws + off);  off += (size_t)NEXP * HIDDEN * INTER * 2;
  short* wdT = (short*)(ws + off);  off += (size_t)NEXP * HIDDEN * INTER * 2;
  short* hbuf = (short*)(ws + off);
  float* ybuf = (float*)wgT;   // wgT+wuT dead after gateup; 32 MB fits in 46 MB

  hipMemsetAsync(ws, 0, 64, stream);   // counts + base

  convx_kernel<<<(NTOK * HIDDEN / 8) / 256, 256, 0, stream>>>(x, xb);
  {
    dim3 g(INTER / 64, HIDDEN / 64, NEXP);   // wg/wu: K=HIDDEN, N=INTER
    tconv_kernel<<<g, 256, 0, stream>>>(wg, wgT, HIDDEN, INTER);
    tconv_kernel<<<g, 256, 0, stream>>>(wu, wuT, HIDDEN, INTER);
  }
  {
    dim3 g(HIDDEN / 64, INTER / 64, NEXP);   // wd: K=INTER, N=HIDDEN
    tconv_kernel<<<g, 256, 0, stream>>>(wd, wdT, INTER, HIDDEN);
  }

  router_kernel<<<NTOK / 4, 256, 0, stream>>>(x, rw, counts, tok_list, w_list);
  prefix_kernel<<<1, 64, 0, stream>>>(counts, base);

  gateup_mfma<<<8 * 16 * 11, 256, 0, stream>>>(xb, wgT, wuT, counts, base, tok_list, hbuf);
  down_mfma<<<8 * 16 * 16, 256, 0, stream>>>(hbuf, wdT, counts, base, tok_list, w_list, ybuf);

  combine_kernel<<<(NTOK * HIDDEN / 4) / 256, 256, 0, stream>>>(ybuf, out);
}

// Round 5
// 276.945 us; speedup vs baseline: 1.3705x; 1.1791x over previous
//
#include <hip/hip_runtime.h>
#include <math.h>

#define HIDDEN 1024
#define INTER  1408
#define NEXP   8
#define NTOK   2048
#define KSPLIT_LEN 704   // INTER/2

typedef short s16x8 __attribute__((ext_vector_type(8)));   // 8 bf16 MFMA operand
typedef float f32x4 __attribute__((ext_vector_type(4)));   // MFMA accumulator

static __device__ __forceinline__ short f2b(float f) {
  union { float f; unsigned u; } v; v.f = f;
  unsigned u = v.u;
  unsigned r = (u + 0x7FFFu + ((u >> 16) & 1u)) >> 16;   // RNE
  return (short)r;
}

// ---------------------------------------------------------------------------
// Router phase 1: one wave per token, fp32 exact, NO atomics.
// Writes per-token choice: ce[t] = e0 | e1<<8, cw[t] = (w0, w1).
// ---------------------------------------------------------------------------
__global__ __launch_bounds__(256) void router_choice(
    const float* __restrict__ x, const float* __restrict__ rw,
    int* __restrict__ ce, float2* __restrict__ cw)
{
  int wave = threadIdx.x >> 6;
  int lane = threadIdx.x & 63;
  int t = blockIdx.x * 4 + wave;
  if (t >= NTOK) return;
  const float* xt = x + (size_t)t * HIDDEN;
  float xr[16];
#pragma unroll
  for (int i = 0; i < 16; ++i) xr[i] = xt[lane + 64 * i];
  float logits[NEXP];
#pragma unroll
  for (int e = 0; e < NEXP; ++e) {
    const float* w = rw + e * HIDDEN;
    float acc = 0.f;
#pragma unroll
    for (int i = 0; i < 16; ++i) acc = fmaf(xr[i], w[lane + 64 * i], acc);
#pragma unroll
    for (int off = 32; off > 0; off >>= 1) acc += __shfl_xor(acc, off);
    logits[e] = acc;
  }
  if (lane == 0) {
    float mx = logits[0];
#pragma unroll
    for (int e = 1; e < NEXP; ++e) mx = fmaxf(mx, logits[e]);
    float p[NEXP];
#pragma unroll
    for (int e = 0; e < NEXP; ++e) p[e] = expf(logits[e] - mx);
    int i0 = 0;
#pragma unroll
    for (int e = 1; e < NEXP; ++e) if (p[e] > p[i0]) i0 = e;
    int i1 = (i0 == 0) ? 1 : 0;
#pragma unroll
    for (int e = 0; e < NEXP; ++e) { if (e != i0 && p[e] > p[i1]) i1 = e; }
    float denom = p[i0] + p[i1];
    ce[t] = i0 | (i1 << 8);
    cw[t] = make_float2(p[i0] / denom, p[i1] / denom);
  }
}

// ---------------------------------------------------------------------------
// Router phase 2: one block per expert. Deterministic compaction (stable in
// token order) via register histogram + LDS scan. Also computes counts[e] and
// base[e] (= sum of counts of lower-indexed experts) -> replaces prefix pass.
// ---------------------------------------------------------------------------
__global__ __launch_bounds__(256) void build_lists(
    const int* __restrict__ ce, const float2* __restrict__ cw,
    int* __restrict__ counts, int* __restrict__ base,
    int* __restrict__ tok_list, float* __restrict__ w_list)
{
  int e = blockIdx.x;          // 0..7
  int tid = threadIdx.x;       // each thread owns tokens [8*tid, 8*tid+8)
  __shared__ int hall[256][8];
  __shared__ int hsum[8];
  __shared__ int scan[256];

  int cloc[8];                 // cached choices
  int h[8] = {0,0,0,0,0,0,0,0};
  int myc = 0;
#pragma unroll
  for (int j = 0; j < 8; ++j) {
    int c = ce[tid * 8 + j];
    cloc[j] = c;
    int e0 = c & 255, e1 = (c >> 8) & 255;
    h[e0]++; h[e1]++;
    myc += (e0 == e) + (e1 == e);
  }
#pragma unroll
  for (int k = 0; k < 8; ++k) hall[tid][k] = h[k];
  scan[tid] = myc;
  __syncthreads();

  if (tid < 8) {
    int s = 0;
    for (int i = 0; i < 256; ++i) s += hall[i][tid];
    hsum[tid] = s;
  }
  // Hillis-Steele inclusive scan over per-thread counts
  int v = myc;
  for (int off = 1; off < 256; off <<= 1) {
    int prev = (tid >= off) ? scan[tid - off] : 0;
    __syncthreads();
    v = v + prev;
    scan[tid] = v;
    __syncthreads();
  }
  int pos = v - myc;           // exclusive prefix = my first slot

  if (tid == 0) {
    int b = 0;
    for (int k = 0; k < e; ++k) b += hsum[k];
    base[e] = b;
    counts[e] = hsum[e];
  }

#pragma unroll
  for (int j = 0; j < 8; ++j) {
    int t = tid * 8 + j;
    int c = cloc[j];
    int e0 = c & 255, e1 = (c >> 8) & 255;
    if (e0 == e) {
      float2 w = cw[t];
      tok_list[e * NTOK + pos] = t;                // slot 0
      w_list[e * NTOK + pos] = w.x;
      pos++;
    } else if (e1 == e) {
      float2 w = cw[t];
      tok_list[e * NTOK + pos] = t | (1 << 16);    // slot 1
      w_list[e * NTOK + pos] = w.y;
      pos++;
    }
  }
}

// ---------------------------------------------------------------------------
// Fused prep: x fp32->bf16 copy + three transpose-converts, one flat grid.
//   blocks [0, 1024)            : convx  (8 elems/thread)
//   blocks [1024, 1024+2816)    : wg  [e][1024][1408] -> wgT [e][1408][1024]
//   next 2816                   : wu  likewise
//   next 2816                   : wd  [e][1408][1024] -> wdT [e][1024][1408]
// ---------------------------------------------------------------------------
static __device__ __forceinline__ void tconv_tile(
    const float* __restrict__ ie, short* __restrict__ oe,
    int K, int N, int k0, int n0, int tid, float (*t)[65])
{
  int c4 = (tid & 15) * 4, r = tid >> 4;
#pragma unroll
  for (int p = 0; p < 4; ++p) {
    float4 v = *(const float4*)(ie + (size_t)(k0 + r + p * 16) * N + n0 + c4);
    t[r + p * 16][c4 + 0] = v.x;
    t[r + p * 16][c4 + 1] = v.y;
    t[r + p * 16][c4 + 2] = v.z;
    t[r + p * 16][c4 + 3] = v.w;
  }
  __syncthreads();
  int rn = tid >> 2, ck = (tid & 3) * 16;
  s16x8 o0, o1;
#pragma unroll
  for (int j = 0; j < 8; ++j) o0[j] = f2b(t[ck + j][rn]);
#pragma unroll
  for (int j = 0; j < 8; ++j) o1[j] = f2b(t[ck + 8 + j][rn]);
  short* op = oe + (size_t)(n0 + rn) * K + k0 + ck;
  *(s16x8*)(op) = o0;
  *(s16x8*)(op + 8) = o1;
}

__global__ __launch_bounds__(256) void prep_kernel(
    const float* __restrict__ x, const float* __restrict__ wg,
    const float* __restrict__ wu, const float* __restrict__ wd,
    short* __restrict__ xb, short* __restrict__ wgT,
    short* __restrict__ wuT, short* __restrict__ wdT)
{
  __shared__ float t[64][65];
  int id = blockIdx.x;
  int tid = threadIdx.x;
  if (id < 1024) {
    size_t i = (size_t)id * 256 + tid;
    const float4* p = (const float4*)x;
    float4 a = p[2 * i], b = p[2 * i + 1];
    s16x8 o;
    o[0] = f2b(a.x); o[1] = f2b(a.y); o[2] = f2b(a.z); o[3] = f2b(a.w);
    o[4] = f2b(b.x); o[5] = f2b(b.y); o[6] = f2b(b.z); o[7] = f2b(b.w);
    *(s16x8*)(xb + 8 * i) = o;
    return;
  }
  int id2 = id - 1024;
  int seg = id2 / 2816;       // 0: wg, 1: wu, 2: wd
  int r = id2 - seg * 2816;
  int e = r / 352;
  int rem = r - e * 352;
  if (seg < 2) {
    // K=1024 (HIDDEN), N=1408 (INTER): 16 k-tiles x 22 n-tiles
    int kt = rem / 22, nt = rem - kt * 22;
    const float* ie = (seg == 0 ? wg : wu) + (size_t)e * HIDDEN * INTER;
    short* oe = (seg == 0 ? wgT : wuT) + (size_t)e * HIDDEN * INTER;
    tconv_tile(ie, oe, HIDDEN, INTER, kt * 64, nt * 64, tid, t);
  } else {
    // K=1408 (INTER), N=1024 (HIDDEN): 22 k-tiles x 16 n-tiles
    int kt = rem >> 4, nt = rem & 15;
    const float* ie = wd + (size_t)e * HIDDEN * INTER;
    short* oe = wdT + (size_t)e * HIDDEN * INTER;
    tconv_tile(ie, oe, INTER, HIDDEN, kt * 64, nt * 64, tid, t);
  }
}

// ---------------------------------------------------------------------------
// Staging geometry (both GEMMs), XOR-swizzled LDS [row][4 chunks]:
//   phys chunk p of row r holds logical chunk p ^ ((r>>1)&3); fragment read
//   (lane ml, quad q) uses phys q ^ ((ml>>1)&3) -> 2-way aliasing only (free).
//   Measured 0 LDS bank conflicts (r3/r4).
// ---------------------------------------------------------------------------

// ---------------------------------------------------------------------------
// Phase A: H = silu(X@Wg)*(X@Wu). Tile M=128 N=128 BK=32, 4 waves (2x2),
// 4x4 MFMAs each for gate AND up; register prefetch issued after the
// LDS-ready barrier. XCD-swizzled flat grid for weight-strip L2 locality.
// ---------------------------------------------------------------------------
__global__ __launch_bounds__(256, 2) void gateup_mfma(
    const short* __restrict__ xb, const short* __restrict__ wgT,
    const short* __restrict__ wuT,
    const int* __restrict__ counts, const int* __restrict__ base,
    const int* __restrict__ tok_list, short* __restrict__ hbuf)
{
  // grid = 8 xcd * 16 m * 11 g-hi = 1408; g = (e,n) in 0..87
  int id = blockIdx.x;
  int xcd = id & 7;
  int rest = id >> 3;
  int mslot = rest & 15;
  int g = (rest >> 4) * 8 + xcd;
  int e = g / 11;
  int n0 = (g - e * 11) * 128;
  int cnt = counts[e];
  int m0 = mslot * 128;
  if (m0 >= cnt) return;

  __shared__ short As[128 * 32];
  __shared__ short Bg[128 * 32];
  __shared__ short Bu[128 * 32];
  __shared__ int toks[128];

  int tid = threadIdx.x;
  if (tid < 128) {
    int r = m0 + tid;
    toks[tid] = tok_list[e * NTOK + (r < cnt ? r : cnt - 1)] & 0xFFFF;
  }
  __syncthreads();

  int sr = tid >> 1;             // 0..127
  int h = tid & 1;
  int key = (sr >> 1) & 3;
  int pair = ((2 * h) ^ key) >> 1;           // which 32B global block
  int sw = (key & 1) * 8;                    // swap c0/c1 on write
  const short* gA = xb + (size_t)toks[sr] * HIDDEN + pair * 16;
  const short* gG = wgT + ((size_t)e * INTER + n0 + sr) * HIDDEN + pair * 16;
  const short* gU = wuT + ((size_t)e * INTER + n0 + sr) * HIDDEN + pair * 16;
  short* wA0 = &As[sr * 32 + h * 16 + sw];
  short* wA1 = &As[sr * 32 + h * 16 + (8 - sw)];
  short* wG0 = &Bg[sr * 32 + h * 16 + sw];
  short* wG1 = &Bg[sr * 32 + h * 16 + (8 - sw)];
  short* wU0 = &Bu[sr * 32 + h * 16 + sw];
  short* wU1 = &Bu[sr * 32 + h * 16 + (8 - sw)];

  int wv = tid >> 6, lane = tid & 63;
  int wm = wv & 1, wn = wv >> 1;
  int q = lane >> 4, ml = lane & 15;
  int chk = q ^ ((ml >> 1) & 3);
  const short* ard = &As[(wm * 64 + ml) * 32 + chk * 8];
  const short* grd = &Bg[(wn * 64 + ml) * 32 + chk * 8];
  const short* urd = &Bu[(wn * 64 + ml) * 32 + chk * 8];

  f32x4 accg[4][4], accu[4][4];
#pragma unroll
  for (int i = 0; i < 4; ++i)
#pragma unroll
    for (int j = 0; j < 4; ++j) { accg[i][j] = (f32x4)0.f; accu[i][j] = (f32x4)0.f; }

  s16x8 a0 = *(const s16x8*)(gA);     s16x8 a1 = *(const s16x8*)(gA + 8);
  s16x8 g0 = *(const s16x8*)(gG);     s16x8 g1 = *(const s16x8*)(gG + 8);
  s16x8 u0 = *(const s16x8*)(gU);     s16x8 u1 = *(const s16x8*)(gU + 8);

  for (int k0 = 0; k0 < HIDDEN; k0 += 32) {
    __syncthreads();
    *(s16x8*)wA0 = a0; *(s16x8*)wA1 = a1;
    *(s16x8*)wG0 = g0; *(s16x8*)wG1 = g1;
    *(s16x8*)wU0 = u0; *(s16x8*)wU1 = u1;
    __syncthreads();

    int kn = (k0 + 32) & (HIDDEN - 1);
    a0 = *(const s16x8*)(gA + kn);     a1 = *(const s16x8*)(gA + kn + 8);
    g0 = *(const s16x8*)(gG + kn);     g1 = *(const s16x8*)(gG + kn + 8);
    u0 = *(const s16x8*)(gU + kn);     u1 = *(const s16x8*)(gU + kn + 8);

    s16x8 af[4], gf[4], uf[4];
#pragma unroll
    for (int i = 0; i < 4; ++i) af[i] = *(const s16x8*)(ard + i * 16 * 32);
#pragma unroll
    for (int j = 0; j < 4; ++j) {
      gf[j] = *(const s16x8*)(grd + j * 16 * 32);
      uf[j] = *(const s16x8*)(urd + j * 16 * 32);
    }
#pragma unroll
    for (int i = 0; i < 4; ++i)
#pragma unroll
      for (int j = 0; j < 4; ++j) {
        accg[i][j] = __builtin_amdgcn_mfma_f32_16x16x32_bf16(af[i], gf[j], accg[i][j], 0, 0, 0);
        accu[i][j] = __builtin_amdgcn_mfma_f32_16x16x32_bf16(af[i], uf[j], accu[i][j], 0, 0, 0);
      }
  }

  int hb = base[e];
#pragma unroll
  for (int i = 0; i < 4; ++i)
#pragma unroll
    for (int ii = 0; ii < 4; ++ii) {
      int r = m0 + wm * 64 + i * 16 + q * 4 + ii;
      if (r < cnt) {
        short* hp = hbuf + (size_t)(hb + r) * INTER + n0 + wn * 64 + ml;
#pragma unroll
        for (int j = 0; j < 4; ++j) {
          float gg = accg[i][j][ii], uu = accu[i][j][ii];
          float hh = (gg / (1.f + __expf(-gg))) * uu;
          hp[j * 16] = f2b(hh);
        }
      }
    }
}

// ---------------------------------------------------------------------------
// Phase B: Y = H @ Wd, K-split x2; scaled partials to ybuf[slot*2+ks][token]
// with plain stores (no atomics).
// ---------------------------------------------------------------------------
__global__ __launch_bounds__(256, 3) void down_mfma(
    const short* __restrict__ hbuf, const short* __restrict__ wdT,
    const int* __restrict__ counts, const int* __restrict__ base,
    const int* __restrict__ tok_list, const float* __restrict__ w_list,
    float* __restrict__ ybuf)
{
  // grid = 8 xcd * 16 m * 16 g-hi = 2048; g = (e,ks,n) in 0..127
  int id = blockIdx.x;
  int xcd = id & 7;
  int rest = id >> 3;
  int mslot = rest & 15;
  int g = (rest >> 4) * 8 + xcd;
  int e = g >> 4;
  int ks = (g >> 3) & 1;
  int n0 = (g & 7) * 128;
  int cnt = counts[e];
  int m0 = mslot * 128;
  if (m0 >= cnt) return;

  __shared__ short As[128 * 32];
  __shared__ short Bs[128 * 32];

  int tid = threadIdx.x;
  int hb = base[e];
  int kbeg = ks * KSPLIT_LEN, kend = kbeg + KSPLIT_LEN;

  int sr = tid >> 1;
  int h = tid & 1;
  int key = (sr >> 1) & 3;
  int pair = ((2 * h) ^ key) >> 1;
  int sw = (key & 1) * 8;
  int ra = m0 + sr; if (ra >= cnt) ra = cnt - 1;
  const short* gA = hbuf + (size_t)(hb + ra) * INTER + pair * 16;
  const short* gB = wdT + ((size_t)e * HIDDEN + n0 + sr) * INTER + pair * 16;
  short* wA0 = &As[sr * 32 + h * 16 + sw];
  short* wA1 = &As[sr * 32 + h * 16 + (8 - sw)];
  short* wB0 = &Bs[sr * 32 + h * 16 + sw];
  short* wB1 = &Bs[sr * 32 + h * 16 + (8 - sw)];

  int wv = tid >> 6, lane = tid & 63;
  int wm = wv & 1, wn = wv >> 1;
  int q = lane >> 4, ml = lane & 15;
  int chk = q ^ ((ml >> 1) & 3);
  const short* ard = &As[(wm * 64 + ml) * 32 + chk * 8];
  const short* brd = &Bs[(wn * 64 + ml) * 32 + chk * 8];

  f32x4 acc[4][4];
#pragma unroll
  for (int i = 0; i < 4; ++i)
#pragma unroll
    for (int j = 0; j < 4; ++j) acc[i][j] = (f32x4)0.f;

  s16x8 a0 = *(const s16x8*)(gA + kbeg);  s16x8 a1 = *(const s16x8*)(gA + kbeg + 8);
  s16x8 b0 = *(const s16x8*)(gB + kbeg);  s16x8 b1 = *(const s16x8*)(gB + kbeg + 8);

  for (int k0 = kbeg; k0 < kend; k0 += 32) {
    __syncthreads();
    *(s16x8*)wA0 = a0; *(s16x8*)wA1 = a1;
    *(s16x8*)wB0 = b0; *(s16x8*)wB1 = b1;
    __syncthreads();

    int kn = k0 + 32; if (kn >= kend) kn = kbeg;
    a0 = *(const s16x8*)(gA + kn);  a1 = *(const s16x8*)(gA + kn + 8);
    b0 = *(const s16x8*)(gB + kn);  b1 = *(const s16x8*)(gB + kn + 8);

    s16x8 af[4], bf[4];
#pragma unroll
    for (int i = 0; i < 4; ++i) af[i] = *(const s16x8*)(ard + i * 16 * 32);
#pragma unroll
    for (int j = 0; j < 4; ++j) bf[j] = *(const s16x8*)(brd + j * 16 * 32);
#pragma unroll
    for (int i = 0; i < 4; ++i)
#pragma unroll
      for (int j = 0; j < 4; ++j)
        acc[i][j] = __builtin_amdgcn_mfma_f32_16x16x32_bf16(af[i], bf[j], acc[i][j], 0, 0, 0);
  }

#pragma unroll
  for (int i = 0; i < 4; ++i)
#pragma unroll
    for (int ii = 0; ii < 4; ++ii) {
      int r = m0 + wm * 64 + i * 16 + q * 4 + ii;
      if (r < cnt) {
        int ent = tok_list[e * NTOK + r];
        int tok = ent & 0xFFFF, slot = ent >> 16;
        float wgt = w_list[e * NTOK + r];
        float* yp = ybuf + ((size_t)(slot * 2 + ks) * NTOK + tok) * HIDDEN
                    + n0 + wn * 64 + ml;
#pragma unroll
        for (int j = 0; j < 4; ++j)
          yp[j * 16] = acc[i][j][ii] * wgt;
      }
    }
}

// ---------------------------------------------------------------------------
// out = sum of 4 ybuf slabs (every element written -> no out memset needed)
// ---------------------------------------------------------------------------
__global__ __launch_bounds__(256) void combine_kernel(
    const float* __restrict__ ybuf, float* __restrict__ out)
{
  size_t i = (size_t)blockIdx.x * 256 + threadIdx.x;
  const size_t S = (size_t)NTOK * HIDDEN / 4;
  float4 a = ((const float4*)ybuf)[i];
  float4 b = ((const float4*)ybuf)[i + S];
  float4 c = ((const float4*)ybuf)[i + 2 * S];
  float4 d = ((const float4*)ybuf)[i + 3 * S];
  float4 o;
  o.x = (a.x + b.x) + (c.x + d.x);
  o.y = (a.y + b.y) + (c.y + d.y);
  o.z = (a.z + b.z) + (c.z + d.z);
  o.w = (a.w + b.w) + (c.w + d.w);
  ((float4*)out)[i] = o;
}

// ---------------------------------------------------------------------------
// ws layout (bytes):
//   0..32           counts[8]
//   32..64          base[8]
//   64..65600       tok_list[8][2048]  (token | slot<<16)
//   65600..131136   w_list[8][2048]
//   131136..139328  ce[2048]
//   139328..155712  cw[2048] float2
//   155712          xb   bf16 [2048][1024]      (4 MB)
//   +4 MB           wgT  bf16 [8][1408][1024]   (23.07 MB) } ybuf[4] (32 MB
//   +23.07 MB       wuT  bf16 [8][1408][1024]   (23.07 MB) } fp32) aliases
//                                                          } wgT+wuT after
//                                                          } gateup completes
//   +23.07 MB       wdT  bf16 [8][1024][1408]
//   +23.07 MB       hbuf bf16 [4096][1408]      (11.5 MB)
//   total ~85.2 MB
// ---------------------------------------------------------------------------
extern "C" void kernel_launch(void* const* d_in, const int* in_sizes, int n_in,
                              void* d_out, int out_size, void* d_ws, size_t ws_size,
                              hipStream_t stream)
{
  const float* x  = (const float*)d_in[0];
  const float* rw = (const float*)d_in[1];
  const float* wg = (const float*)d_in[2];
  const float* wu = (const float*)d_in[3];
  const float* wd = (const float*)d_in[4];
  float* out = (float*)d_out;

  char* ws = (char*)d_ws;
  int*    counts   = (int*)(ws);
  int*    base     = (int*)(ws + 32);
  int*    tok_list = (int*)(ws + 64);
  float*  w_list   = (float*)(ws + 64 + NEXP * NTOK * 4);
  size_t off = 64 + 2 * (size_t)NEXP * NTOK * 4;
  int*    ce = (int*)(ws + off);     off += NTOK * 4;
  float2* cw = (float2*)(ws + off);  off += NTOK * 8;
  short* xb  = (short*)(ws + off);  off += (size_t)NTOK * HIDDEN * 2;
  short* wgT = (short*)(ws + off);  off += (size_t)NEXP * HIDDEN * INTER * 2;
  short* wuT = (short*)(ws + off);  off += (size_t)NEXP * HIDDEN * INTER * 2;
  short* wdT = (short*)(ws + off);  off += (size_t)NEXP * HIDDEN * INTER * 2;
  short* hbuf = (short*)(ws + off);
  float* ybuf = (float*)wgT;   // wgT+wuT dead after gateup; 32 MB fits in 46 MB

  router_choice<<<NTOK / 4, 256, 0, stream>>>(x, rw, ce, cw);
  build_lists<<<NEXP, 256, 0, stream>>>(ce, cw, counts, base, tok_list, w_list);

  prep_kernel<<<1024 + 3 * 2816, 256, 0, stream>>>(x, wg, wu, wd, xb, wgT, wuT, wdT);

  gateup_mfma<<<8 * 16 * 11, 256, 0, stream>>>(xb, wgT, wuT, counts, base, tok_list, hbuf);
  down_mfma<<<8 * 16 * 16, 256, 0, stream>>>(hbuf, wdT, counts, base, tok_list, w_list, ybuf);

  combine_kernel<<<(NTOK * HIDDEN / 4) / 256, 256, 0, stream>>>(ybuf, out);
}